// Round 3
// baseline (1437.233 us; speedup 1.0000x reference)
//
#include <hip/hip_runtime.h>
#include <math.h>

#define TB 32
#define TT 1000
#define TD 512
#define TU 5
#define TT1 1001

// d_out float offsets (return order: acoustic, token_num, alphas_t, cif_peak, token_num2)
#define OFF_ACC  0
#define OFF_TOKN 16400384
#define OFF_ALPH 16400416
#define OFF_PEAK 16432448
#define OFF_TOK2 16464480

// ---------------- init: zero partial-dot accumulators + token_num2 ----------------
__global__ __launch_bounds__(256) void kzero(float* araw1, float* araw2, float* tok2) {
    int idx = blockIdx.x * 256 + threadIdx.x;
    int stride = gridDim.x * 256;
    for (int i = idx; i < TB * TT; i += stride) araw1[i] = 0.f;
    for (int i = idx; i < TB * TT * TU; i += stride) araw2[i] = 0.f;
    if (idx < TB) tok2[idx] = 0.f;
}

// ---------------- c2 = b2 + dot(up_b, w2) ----------------
__global__ __launch_bounds__(256) void kc2(const float* __restrict__ up_b, const float* __restrict__ w2,
                                           const float* __restrict__ b2, float* __restrict__ c2out) {
    int tid = threadIdx.x;
    float p = 0.f;
    for (int o = tid; o < TD; o += 256) p += up_b[o] * w2[o];
#pragma unroll
    for (int m = 1; m < 64; m <<= 1) p += __shfl_xor(p, m);
    __shared__ float wsum[4];
    if ((tid & 63) == 0) wsum[tid >> 6] = p;
    __syncthreads();
    if (tid == 0) c2out[0] = b2[0] + wsum[0] + wsum[1] + wsum[2] + wsum[3];
}

// ---------------- v[i][j] = sum_o up_w[i][o][j] * w2[o] ----------------
__global__ __launch_bounds__(64) void kv(const float* __restrict__ up_w, const float* __restrict__ w2,
                                         float* __restrict__ vmat) {
    int i = blockIdx.x, lane = threadIdx.x;
    float s0 = 0, s1 = 0, s2 = 0, s3 = 0, s4 = 0;
    for (int o = lane; o < TD; o += 64) {
        float w = w2[o];
        const float* p = up_w + (size_t)i * (TD * TU) + o * TU;
        s0 += p[0] * w; s1 += p[1] * w; s2 += p[2] * w; s3 += p[3] * w; s4 += p[4] * w;
    }
#pragma unroll
    for (int m = 1; m < 64; m <<= 1) {
        s0 += __shfl_xor(s0, m); s1 += __shfl_xor(s1, m); s2 += __shfl_xor(s2, m);
        s3 += __shfl_xor(s3, m); s4 += __shfl_xor(s4, m);
    }
    if (lane == 0) {
        float* d = vmat + i * TU;
        d[0] = s0; d[1] = s1; d[2] = s2; d[3] = s3; d[4] = s4;
    }
}

// ---------------- conv1d(K=3,pad=1)+bias+relu -> 6 dots per (b,t), scalar-weight form ----
// Block: 256 threads, lane owns frame t = t0 + tid. o-chunk of 32 out-channels per block.
// Weights are wave-uniform -> SGPR s_load (off the LDS/VALU pipes).
// Activations: [16 ch][258 frames] LDS window; 3 conflict-free ds_read_b32 per ch,
// reused across 32 o x 3 k = 96 FMAs.
#define XSTR 265  // LDS row stride: bank(i*265+s) = (9i+s)%32, distinct for i=0..15 -> conflict-free
__global__ __launch_bounds__(256) void kconv(const float* __restrict__ enc, const float* __restrict__ cw,
                                             const float* __restrict__ cb, const float* __restrict__ w1,
                                             const float* __restrict__ vmat,
                                             float* __restrict__ araw1, float* __restrict__ araw2) {
    __shared__ float sX[16 * XSTR];

    const int tid = threadIdx.x;
    const int t0 = blockIdx.x * 256;
    const int o0 = blockIdx.y * 32;
    const int b = blockIdx.z;

    float acc[32];
#pragma unroll
    for (int o = 0; o < 32; ++o) acc[o] = 0.f;

    for (int i0 = 0; i0 < TD; i0 += 16) {
        __syncthreads();
        // stage enc window: s in [0,258) -> t = t0-1+s, 16 channels, zero-padded
        for (int u = tid; u < 258 * 4; u += 256) {
            int s = u >> 2, q = u & 3;
            int t = t0 - 1 + s;
            float4 v = make_float4(0.f, 0.f, 0.f, 0.f);
            if (t >= 0 && t < TT) v = *(const float4*)&enc[((size_t)b * TT + t) * TD + i0 + q * 4];
            float* d = &sX[(q * 4) * XSTR + s];
            d[0] = v.x; d[XSTR] = v.y; d[2 * XSTR] = v.z; d[3 * XSTR] = v.w;
        }
        __syncthreads();

        const float* wbase = cw + (size_t)o0 * (TD * 3) + i0 * 3;  // uniform
#pragma unroll
        for (int ii = 0; ii < 16; ++ii) {
            float x0 = sX[ii * XSTR + tid];      // t-1
            float x1 = sX[ii * XSTR + tid + 1];  // t
            float x2 = sX[ii * XSTR + tid + 2];  // t+1
#pragma unroll
            for (int o = 0; o < 32; ++o) {
                const float* wp = wbase + o * (TD * 3) + ii * 3;  // uniform -> s_load
                acc[o] = fmaf(wp[0], x0, acc[o]);
                acc[o] = fmaf(wp[1], x1, acc[o]);
                acc[o] = fmaf(wp[2], x2, acc[o]);
            }
        }
    }

    // epilogue: bias+relu, reduce this o-chunk into the 6 per-frame dots
    float s1 = 0.f, sa = 0.f, sb = 0.f, sc = 0.f, sd = 0.f, se = 0.f;
#pragma unroll
    for (int o = 0; o < 32; ++o) {
        int og = o0 + o;  // uniform
        float r = fmaxf(acc[o] + cb[og], 0.f);
        s1 = fmaf(w1[og], r, s1);
        const float* vp = vmat + og * 5;
        sa = fmaf(vp[0], r, sa);
        sb = fmaf(vp[1], r, sb);
        sc = fmaf(vp[2], r, sc);
        sd = fmaf(vp[3], r, sd);
        se = fmaf(vp[4], r, se);
    }
    int t = t0 + tid;
    if (t < TT) {
        atomicAdd(&araw1[b * TT + t], s1);
        float* p2 = &araw2[(b * TT + t) * 5];
        atomicAdd(p2 + 0, sa); atomicAdd(p2 + 1, sb); atomicAdd(p2 + 2, sc);
        atomicAdd(p2 + 3, sd); atomicAdd(p2 + 4, se);
    }
}

// ---------------- alphas_t (with tail), token_num2 ----------------
__global__ __launch_bounds__(256) void kalpha(const float* __restrict__ araw1, const float* __restrict__ araw2,
                                              const float* __restrict__ mask, const float* __restrict__ b1,
                                              const float* __restrict__ c2,
                                              float* __restrict__ alphas_t, float* __restrict__ tok2) {
    int b = blockIdx.y;
    int t = blockIdx.x * 256 + threadIdx.x;
    float sum5 = 0.f;
    if (t < TT) {
        float mk = mask[b * TT + t];
        float a1 = araw1[b * TT + t] + b1[0];
        float alpha = mk / (1.f + expf(-a1));
        float mprev = (t == 0) ? 1.f : mask[b * TT + t - 1];
        float tail = (mprev - mk) * 0.45f;
        alphas_t[b * TT1 + t] = alpha + tail;
        float cc = c2[0];
        float x0 = araw2[(b * TT + t) * 5 + 0] + cc;
        float x1 = araw2[(b * TT + t) * 5 + 1] + cc;
        float x2 = araw2[(b * TT + t) * 5 + 2] + cc;
        float x3 = araw2[(b * TT + t) * 5 + 3] + cc;
        float x4 = araw2[(b * TT + t) * 5 + 4] + cc;
        sum5 = mk / (1.f + expf(-x0)) + mk / (1.f + expf(-x1)) + mk / (1.f + expf(-x2))
             + mk / (1.f + expf(-x3)) + mk / (1.f + expf(-x4));
    } else if (t == TT) {
        alphas_t[b * TT1 + TT] = mask[b * TT + TT - 1] * 0.45f;
    }
#pragma unroll
    for (int m = 1; m < 64; m <<= 1) sum5 += __shfl_xor(sum5, m);
    if ((threadIdx.x & 63) == 0) atomicAdd(&tok2[b], sum5);
}

// ---------------- sequential CIF scan (faithful to reference fp32 op order) ----------------
__global__ __launch_bounds__(64) void kscan(const float* __restrict__ alphas_t,
                                            float* __restrict__ cif_peak, float* __restrict__ token_num,
                                            float* __restrict__ wA, float* __restrict__ wB,
                                            int* __restrict__ fire_time, int* __restrict__ n_fires) {
    int b = blockIdx.x, lane = threadIdx.x;
    float integ = 0.f, Ssum = 0.f;
    int F = 0;
    for (int c = 0; c < 16; ++c) {
        int t = c * 64 + lane;
        float av = (t < TT1) ? alphas_t[b * TT1 + t] : 0.f;
        float myPeak = 0.f, myWA = 0.f, myWB = 0.f;
        int myFire = 0, myF = 0;
        for (int j = 0; j < 64; ++j) {
            float a = __shfl(av, j);
            if (c * 64 + j < TT1) {
                float dist = 1.f - integ;
                integ += a;
                float peak = integ;
                bool fire = integ >= 1.f;
                float cur = fire ? dist : a;
                if (lane == j) {
                    myPeak = peak;
                    myWA = cur;
                    myWB = fire ? (a - cur) : 0.f;
                    myFire = fire ? 1 : 0;
                    myF = F;
                }
                if (fire) { integ -= 1.f; F++; }
                Ssum += a;
            }
        }
        if (t < TT1) {
            cif_peak[b * TT1 + t] = myPeak;
            wA[b * TT1 + t] = myWA;
            wB[b * TT1 + t] = myWB;
            if (myFire) fire_time[b * TT1 + myF] = t;
        }
    }
    if (lane == 0) {
        token_num[b] = floorf(Ssum);
        n_fires[b] = F;
    }
}

// ---------------- gather: acoustic[b,k,:] = segmented weighted sum of encoder rows ----------------
__global__ __launch_bounds__(128) void kgather(const float* __restrict__ enc,
                                               const float* __restrict__ wA, const float* __restrict__ wB,
                                               const int* __restrict__ fire_time, const int* __restrict__ n_fires,
                                               float* __restrict__ acoustic) {
    int k = blockIdx.x, b = blockIdx.y;
    int d4 = threadIdx.x;
    float ox = 0.f, oy = 0.f, oz = 0.f, ow = 0.f;
    int nf = n_fires[b];
    if (k < nf) {
        int end = fire_time[b * TT1 + k];
        int start = (k > 0) ? fire_time[b * TT1 + k - 1] : 0;
        for (int t = start; t <= end; ++t) {
            if (t >= TT) continue;
            float w = (k > 0 && t == start) ? wB[b * TT1 + t] : wA[b * TT1 + t];
            float4 h = ((const float4*)(enc + ((size_t)b * TT + t) * TD))[d4];
            ox += w * h.x; oy += w * h.y; oz += w * h.z; ow += w * h.w;
        }
    }
    float4 o4; o4.x = ox; o4.y = oy; o4.z = oz; o4.w = ow;
    ((float4*)(acoustic + ((size_t)b * TT1 + k) * TD))[d4] = o4;
}

extern "C" void kernel_launch(void* const* d_in, const int* in_sizes, int n_in,
                              void* d_out, int out_size, void* d_ws, size_t ws_size,
                              hipStream_t stream) {
    (void)in_sizes; (void)n_in; (void)out_size; (void)ws_size;
    const float* enc = (const float*)d_in[0];
    const float* mask = (const float*)d_in[1];
    const float* cw = (const float*)d_in[2];
    const float* cb = (const float*)d_in[3];
    const float* upw = (const float*)d_in[4];
    const float* upb = (const float*)d_in[5];
    const float* w1 = (const float*)d_in[6];
    const float* b1 = (const float*)d_in[7];
    const float* w2 = (const float*)d_in[8];
    const float* b2 = (const float*)d_in[9];

    float* out = (float*)d_out;
    float* acoustic = out + OFF_ACC;
    float* token_num = out + OFF_TOKN;
    float* alphas_t = out + OFF_ALPH;
    float* cif_peak = out + OFF_PEAK;
    float* tok2 = out + OFF_TOK2;

    float* ws = (float*)d_ws;
    float* araw1 = ws;                       // 32*1000
    float* araw2 = araw1 + TB * TT;          // 32*1000*5
    float* vmat = araw2 + TB * TT * TU;      // 512*5
    float* c2 = vmat + TD * TU;              // 1 (pad to 4)
    float* wA = c2 + 4;                      // 32*1001
    float* wB = wA + TB * TT1;               // 32*1001
    int* fire_time = (int*)(wB + TB * TT1);  // 32*1001
    int* n_fires = fire_time + TB * TT1;     // 32

    hipLaunchKernelGGL(kzero, dim3(256), dim3(256), 0, stream, araw1, araw2, tok2);
    hipLaunchKernelGGL(kc2, dim3(1), dim3(256), 0, stream, upb, w2, b2, c2);
    hipLaunchKernelGGL(kv, dim3(TD), dim3(64), 0, stream, upw, w2, vmat);
    hipLaunchKernelGGL(kconv, dim3(4, 16, TB), dim3(256), 0, stream, enc, cw, cb, w1, vmat, araw1, araw2);
    hipLaunchKernelGGL(kalpha, dim3(4, TB), dim3(256), 0, stream, araw1, araw2, mask, b1, c2, alphas_t, tok2);
    hipLaunchKernelGGL(kscan, dim3(TB), dim3(64), 0, stream, alphas_t, cif_peak, token_num, wA, wB, fire_time, n_fires);
    hipLaunchKernelGGL(kgather, dim3(TT1, TB), dim3(128), 0, stream, enc, wA, wB, fire_time, n_fires, acoustic);
}

// Round 4
// 894.271 us; speedup vs baseline: 1.6072x; 1.6072x over previous
//
#include <hip/hip_runtime.h>
#include <math.h>

#define TB 32
#define TT 1000
#define TD 512
#define TU 5
#define TT1 1001

// d_out float offsets (return order: acoustic, token_num, alphas_t, cif_peak, token_num2)
#define OFF_ACC  0
#define OFF_TOKN 16400384
#define OFF_ALPH 16400416
#define OFF_PEAK 16432448
#define OFF_TOK2 16464480

typedef _Float16 half8 __attribute__((ext_vector_type(8)));
typedef _Float16 half2t __attribute__((ext_vector_type(2)));
typedef float float4t __attribute__((ext_vector_type(4)));

// ---------------- init: zero partial-dot accumulators + token_num2 ----------------
__global__ __launch_bounds__(256) void kzero(float* araw1, float* araw2, float* tok2) {
    int idx = blockIdx.x * 256 + threadIdx.x;
    int stride = gridDim.x * 256;
    for (int i = idx; i < TB * TT; i += stride) araw1[i] = 0.f;
    for (int i = idx; i < TB * TT * TU; i += stride) araw2[i] = 0.f;
    if (idx < TB) tok2[idx] = 0.f;
}

// ---------------- c2 = b2 + dot(up_b, w2) ----------------
__global__ __launch_bounds__(256) void kc2(const float* __restrict__ up_b, const float* __restrict__ w2,
                                           const float* __restrict__ b2, float* __restrict__ c2out) {
    int tid = threadIdx.x;
    float p = 0.f;
    for (int o = tid; o < TD; o += 256) p += up_b[o] * w2[o];
#pragma unroll
    for (int m = 1; m < 64; m <<= 1) p += __shfl_xor(p, m);
    __shared__ float wsum[4];
    if ((tid & 63) == 0) wsum[tid >> 6] = p;
    __syncthreads();
    if (tid == 0) c2out[0] = b2[0] + wsum[0] + wsum[1] + wsum[2] + wsum[3];
}

// ---------------- v[i][j] = sum_o up_w[i][o][j] * w2[o] ----------------
__global__ __launch_bounds__(64) void kv(const float* __restrict__ up_w, const float* __restrict__ w2,
                                         float* __restrict__ vmat) {
    int i = blockIdx.x, lane = threadIdx.x;
    float s0 = 0, s1 = 0, s2 = 0, s3 = 0, s4 = 0;
    for (int o = lane; o < TD; o += 64) {
        float w = w2[o];
        const float* p = up_w + (size_t)i * (TD * TU) + o * TU;
        s0 += p[0] * w; s1 += p[1] * w; s2 += p[2] * w; s3 += p[3] * w; s4 += p[4] * w;
    }
#pragma unroll
    for (int m = 1; m < 64; m <<= 1) {
        s0 += __shfl_xor(s0, m); s1 += __shfl_xor(s1, m); s2 += __shfl_xor(s2, m);
        s3 += __shfl_xor(s3, m); s4 += __shfl_xor(s4, m);
    }
    if (lane == 0) {
        float* d = vmat + i * TU;
        d[0] = s0; d[1] = s1; d[2] = s2; d[3] = s3; d[4] = s4;
    }
}

// ---------------- conv1d via fp16x3-split MFMA ----------------
// Block: 64 o x 256 t, 4 waves; wave = 64 o x 64 t = 4x4 C-tiles of 16x16.
// K-loop over 32-channel chunks; 3 conv taps = B-row address offsets.
// fp32 emulated as Ah*Bh + Ah*Bl + Al*Bh (fp16 hi/lo split, err ~2^-22).
#define BSTR 72    // halves per B row: [h x32][l x32][pad x8]; bank stride 36 dw -> 2-way max
#define ASTR 200   // halves per A row: 3 taps x ([h x32][l x32]) + pad 8; 100 dw -> 2-way max
__global__ __launch_bounds__(256) void kconvM(const float* __restrict__ enc, const float* __restrict__ cw,
                                              const float* __restrict__ cb, const float* __restrict__ w1,
                                              const float* __restrict__ vmat,
                                              float* __restrict__ araw1, float* __restrict__ araw2) {
    __shared__ _Float16 sB[258 * BSTR];  // 37.1 KB  rows: s -> global t = t0-1+s
    __shared__ _Float16 sA[64 * ASTR];   // 25.6 KB  rows: o-local

    const int tid = threadIdx.x;
    const int t0 = blockIdx.x * 256;
    const int o0 = blockIdx.y * 64;
    const int b = blockIdx.z;
    const int wv = tid >> 6, lane = tid & 63;
    const int q = lane >> 4, l15 = lane & 15;

    float4t acc[4][4];
#pragma unroll
    for (int i = 0; i < 4; ++i)
#pragma unroll
        for (int j = 0; j < 4; ++j) acc[i][j] = (float4t){0.f, 0.f, 0.f, 0.f};

    for (int i0 = 0; i0 < TD; i0 += 32) {
        __syncthreads();
        // ---- stage B: enc window rows s=0..257 (t = t0-1+s), 32 channels, split h/l ----
        for (int u = tid; u < 258 * 16; u += 256) {
            int s = u >> 4, ii2 = (u & 15) << 1;
            int t = t0 - 1 + s;
            float x0 = 0.f, x1 = 0.f;
            if (t >= 0 && t < TT) {
                const float* p = &enc[((size_t)b * TT + t) * TD + i0 + ii2];
                x0 = p[0]; x1 = p[1];
            }
            _Float16 h0 = (_Float16)x0, h1 = (_Float16)x1;
            _Float16 l0 = (_Float16)(x0 - (float)h0), l1 = (_Float16)(x1 - (float)h1);
            half2t hh; hh[0] = h0; hh[1] = h1;
            half2t ll; ll[0] = l0; ll[1] = l1;
            *(half2t*)&sB[s * BSTR + ii2] = hh;
            *(half2t*)&sB[s * BSTR + 32 + ii2] = ll;
        }
        // ---- stage A: cw[o0..o0+64][i0..i0+32][k=0..2], split h/l ----
        for (int u = tid; u < 64 * 16; u += 256) {
            int o = u >> 4, ii2 = (u & 15) << 1;
            const float* p = &cw[((size_t)(o0 + o) * TD + i0 + ii2) * 3];
#pragma unroll
            for (int k = 0; k < 3; ++k) {
                float x0 = p[k], x1 = p[3 + k];
                _Float16 h0 = (_Float16)x0, h1 = (_Float16)x1;
                _Float16 l0 = (_Float16)(x0 - (float)h0), l1 = (_Float16)(x1 - (float)h1);
                half2t hh; hh[0] = h0; hh[1] = h1;
                half2t ll; ll[0] = l0; ll[1] = l1;
                *(half2t*)&sA[o * ASTR + k * 64 + ii2] = hh;
                *(half2t*)&sA[o * ASTR + k * 64 + 32 + ii2] = ll;
            }
        }
        __syncthreads();
        // ---- MFMA: 3 taps x 4 ot x 4 tt x 3 products ----
#pragma unroll
        for (int tap = 0; tap < 3; ++tap) {
            half8 Bh[4], Bl[4];
#pragma unroll
            for (int tt = 0; tt < 4; ++tt) {
                int s = wv * 64 + tt * 16 + l15 + tap;  // t_local + tap  (t_global = t0 + t_local + tap - 1)
                Bh[tt] = *(const half8*)&sB[s * BSTR + q * 8];
                Bl[tt] = *(const half8*)&sB[s * BSTR + 32 + q * 8];
            }
#pragma unroll
            for (int ot = 0; ot < 4; ++ot) {
                const int orow = ot * 16 + l15;
                half8 Ah = *(const half8*)&sA[orow * ASTR + tap * 64 + q * 8];
                half8 Al = *(const half8*)&sA[orow * ASTR + tap * 64 + 32 + q * 8];
#pragma unroll
                for (int tt = 0; tt < 4; ++tt) {
                    acc[ot][tt] = __builtin_amdgcn_mfma_f32_16x16x32_f16(Ah, Bh[tt], acc[ot][tt], 0, 0, 0);
                    acc[ot][tt] = __builtin_amdgcn_mfma_f32_16x16x32_f16(Ah, Bl[tt], acc[ot][tt], 0, 0, 0);
                    acc[ot][tt] = __builtin_amdgcn_mfma_f32_16x16x32_f16(Al, Bh[tt], acc[ot][tt], 0, 0, 0);
                }
            }
        }
    }

    // ---- epilogue: r=relu(conv+cb); 6 dots over this block's 64 o; reduce over quads; atomics ----
#pragma unroll
    for (int tt = 0; tt < 4; ++tt) {
        int t = t0 + wv * 64 + tt * 16 + l15;
        float s1 = 0.f, sa = 0.f, sb = 0.f, sc = 0.f, sd = 0.f, se = 0.f;
#pragma unroll
        for (int ot = 0; ot < 4; ++ot) {
#pragma unroll
            for (int r = 0; r < 4; ++r) {
                int o = o0 + ot * 16 + q * 4 + r;  // C row = quad*4 + reg
                float rv = fmaxf(acc[ot][tt][r] + cb[o], 0.f);
                s1 = fmaf(w1[o], rv, s1);
                const float* vp = &vmat[o * 5];
                sa = fmaf(vp[0], rv, sa); sb = fmaf(vp[1], rv, sb);
                sc = fmaf(vp[2], rv, sc); sd = fmaf(vp[3], rv, sd);
                se = fmaf(vp[4], rv, se);
            }
        }
        // reduce across the 4 quads (lane bits 4,5) — same t-column, different o-rows
        s1 += __shfl_xor(s1, 16); sa += __shfl_xor(sa, 16); sb += __shfl_xor(sb, 16);
        sc += __shfl_xor(sc, 16); sd += __shfl_xor(sd, 16); se += __shfl_xor(se, 16);
        s1 += __shfl_xor(s1, 32); sa += __shfl_xor(sa, 32); sb += __shfl_xor(sb, 32);
        sc += __shfl_xor(sc, 32); sd += __shfl_xor(sd, 32); se += __shfl_xor(se, 32);
        if (q == 0 && t < TT) {
            atomicAdd(&araw1[b * TT + t], s1);
            float* p2 = &araw2[(b * TT + t) * 5];
            atomicAdd(p2 + 0, sa); atomicAdd(p2 + 1, sb); atomicAdd(p2 + 2, sc);
            atomicAdd(p2 + 3, sd); atomicAdd(p2 + 4, se);
        }
    }
}

// ---------------- alphas_t (with tail), token_num2 ----------------
__global__ __launch_bounds__(256) void kalpha(const float* __restrict__ araw1, const float* __restrict__ araw2,
                                              const float* __restrict__ mask, const float* __restrict__ b1,
                                              const float* __restrict__ c2,
                                              float* __restrict__ alphas_t, float* __restrict__ tok2) {
    int b = blockIdx.y;
    int t = blockIdx.x * 256 + threadIdx.x;
    float sum5 = 0.f;
    if (t < TT) {
        float mk = mask[b * TT + t];
        float a1 = araw1[b * TT + t] + b1[0];
        float alpha = mk / (1.f + expf(-a1));
        float mprev = (t == 0) ? 1.f : mask[b * TT + t - 1];
        float tail = (mprev - mk) * 0.45f;
        alphas_t[b * TT1 + t] = alpha + tail;
        float cc = c2[0];
        float x0 = araw2[(b * TT + t) * 5 + 0] + cc;
        float x1 = araw2[(b * TT + t) * 5 + 1] + cc;
        float x2 = araw2[(b * TT + t) * 5 + 2] + cc;
        float x3 = araw2[(b * TT + t) * 5 + 3] + cc;
        float x4 = araw2[(b * TT + t) * 5 + 4] + cc;
        sum5 = mk / (1.f + expf(-x0)) + mk / (1.f + expf(-x1)) + mk / (1.f + expf(-x2))
             + mk / (1.f + expf(-x3)) + mk / (1.f + expf(-x4));
    } else if (t == TT) {
        alphas_t[b * TT1 + TT] = mask[b * TT + TT - 1] * 0.45f;
    }
#pragma unroll
    for (int m = 1; m < 64; m <<= 1) sum5 += __shfl_xor(sum5, m);
    if ((threadIdx.x & 63) == 0) atomicAdd(&tok2[b], sum5);
}

// ---------------- sequential CIF scan (faithful to reference fp32 op order) ----------------
__global__ __launch_bounds__(64) void kscan(const float* __restrict__ alphas_t,
                                            float* __restrict__ cif_peak, float* __restrict__ token_num,
                                            float* __restrict__ wA, float* __restrict__ wB,
                                            int* __restrict__ fire_time, int* __restrict__ n_fires) {
    int b = blockIdx.x, lane = threadIdx.x;
    float integ = 0.f, Ssum = 0.f;
    int F = 0;
    for (int c = 0; c < 16; ++c) {
        int t = c * 64 + lane;
        float av = (t < TT1) ? alphas_t[b * TT1 + t] : 0.f;
        float myPeak = 0.f, myWA = 0.f, myWB = 0.f;
        int myFire = 0, myF = 0;
        for (int j = 0; j < 64; ++j) {
            float a = __shfl(av, j);
            if (c * 64 + j < TT1) {
                float dist = 1.f - integ;
                integ += a;
                float peak = integ;
                bool fire = integ >= 1.f;
                float cur = fire ? dist : a;
                if (lane == j) {
                    myPeak = peak;
                    myWA = cur;
                    myWB = fire ? (a - cur) : 0.f;
                    myFire = fire ? 1 : 0;
                    myF = F;
                }
                if (fire) { integ -= 1.f; F++; }
                Ssum += a;
            }
        }
        if (t < TT1) {
            cif_peak[b * TT1 + t] = myPeak;
            wA[b * TT1 + t] = myWA;
            wB[b * TT1 + t] = myWB;
            if (myFire) fire_time[b * TT1 + myF] = t;
        }
    }
    if (lane == 0) {
        token_num[b] = floorf(Ssum);
        n_fires[b] = F;
    }
}

// ---------------- gather: acoustic[b,k,:] = segmented weighted sum of encoder rows ----------------
__global__ __launch_bounds__(128) void kgather(const float* __restrict__ enc,
                                               const float* __restrict__ wA, const float* __restrict__ wB,
                                               const int* __restrict__ fire_time, const int* __restrict__ n_fires,
                                               float* __restrict__ acoustic) {
    int k = blockIdx.x, b = blockIdx.y;
    int d4 = threadIdx.x;
    float ox = 0.f, oy = 0.f, oz = 0.f, ow = 0.f;
    int nf = n_fires[b];
    if (k < nf) {
        int end = fire_time[b * TT1 + k];
        int start = (k > 0) ? fire_time[b * TT1 + k - 1] : 0;
        for (int t = start; t <= end; ++t) {
            if (t >= TT) continue;
            float w = (k > 0 && t == start) ? wB[b * TT1 + t] : wA[b * TT1 + t];
            float4 h = ((const float4*)(enc + ((size_t)b * TT + t) * TD))[d4];
            ox += w * h.x; oy += w * h.y; oz += w * h.z; ow += w * h.w;
        }
    }
    float4 o4; o4.x = ox; o4.y = oy; o4.z = oz; o4.w = ow;
    ((float4*)(acoustic + ((size_t)b * TT1 + k) * TD))[d4] = o4;
}

extern "C" void kernel_launch(void* const* d_in, const int* in_sizes, int n_in,
                              void* d_out, int out_size, void* d_ws, size_t ws_size,
                              hipStream_t stream) {
    (void)in_sizes; (void)n_in; (void)out_size; (void)ws_size;
    const float* enc = (const float*)d_in[0];
    const float* mask = (const float*)d_in[1];
    const float* cw = (const float*)d_in[2];
    const float* cb = (const float*)d_in[3];
    const float* upw = (const float*)d_in[4];
    const float* upb = (const float*)d_in[5];
    const float* w1 = (const float*)d_in[6];
    const float* b1 = (const float*)d_in[7];
    const float* w2 = (const float*)d_in[8];
    const float* b2 = (const float*)d_in[9];

    float* out = (float*)d_out;
    float* acoustic = out + OFF_ACC;
    float* token_num = out + OFF_TOKN;
    float* alphas_t = out + OFF_ALPH;
    float* cif_peak = out + OFF_PEAK;
    float* tok2 = out + OFF_TOK2;

    float* ws = (float*)d_ws;
    float* araw1 = ws;                       // 32*1000
    float* araw2 = araw1 + TB * TT;          // 32*1000*5
    float* vmat = araw2 + TB * TT * TU;      // 512*5
    float* c2 = vmat + TD * TU;              // 1 (pad to 4)
    float* wA = c2 + 4;                      // 32*1001
    float* wB = wA + TB * TT1;               // 32*1001
    int* fire_time = (int*)(wB + TB * TT1);  // 32*1001
    int* n_fires = fire_time + TB * TT1;     // 32

    hipLaunchKernelGGL(kzero, dim3(256), dim3(256), 0, stream, araw1, araw2, tok2);
    hipLaunchKernelGGL(kc2, dim3(1), dim3(256), 0, stream, upb, w2, b2, c2);
    hipLaunchKernelGGL(kv, dim3(TD), dim3(64), 0, stream, upw, w2, vmat);
    hipLaunchKernelGGL(kconvM, dim3(4, 8, TB), dim3(256), 0, stream, enc, cw, cb, w1, vmat, araw1, araw2);
    hipLaunchKernelGGL(kalpha, dim3(4, TB), dim3(256), 0, stream, araw1, araw2, mask, b1, c2, alphas_t, tok2);
    hipLaunchKernelGGL(kscan, dim3(TB), dim3(64), 0, stream, alphas_t, cif_peak, token_num, wA, wB, fire_time, n_fires);
    hipLaunchKernelGGL(kgather, dim3(TT1, TB), dim3(128), 0, stream, enc, wA, wB, fire_time, n_fires, acoustic);
}

// Round 5
// 717.376 us; speedup vs baseline: 2.0035x; 1.2466x over previous
//
#include <hip/hip_runtime.h>
#include <math.h>

#define TB 32
#define TT 1000
#define TD 512
#define TU 5
#define TT1 1001

// d_out float offsets (return order: acoustic, token_num, alphas_t, cif_peak, token_num2)
#define OFF_ACC  0
#define OFF_TOKN 16400384
#define OFF_ALPH 16400416
#define OFF_PEAK 16432448
#define OFF_TOK2 16464480

typedef _Float16 half8 __attribute__((ext_vector_type(8)));
typedef _Float16 half2t __attribute__((ext_vector_type(2)));
typedef float float4t __attribute__((ext_vector_type(4)));

// ---------------- init: zero partial-dot accumulators + token_num2 ----------------
__global__ __launch_bounds__(256) void kzero(float* araw1, float* araw2, float* tok2) {
    int idx = blockIdx.x * 256 + threadIdx.x;
    int stride = gridDim.x * 256;
    for (int i = idx; i < TB * TT; i += stride) araw1[i] = 0.f;
    for (int i = idx; i < TB * TT * TU; i += stride) araw2[i] = 0.f;
    if (idx < TB) tok2[idx] = 0.f;
}

// ---------------- c2 = b2 + dot(up_b, w2) ----------------
__global__ __launch_bounds__(256) void kc2(const float* __restrict__ up_b, const float* __restrict__ w2,
                                           const float* __restrict__ b2, float* __restrict__ c2out) {
    int tid = threadIdx.x;
    float p = 0.f;
    for (int o = tid; o < TD; o += 256) p += up_b[o] * w2[o];
#pragma unroll
    for (int m = 1; m < 64; m <<= 1) p += __shfl_xor(p, m);
    __shared__ float wsum[4];
    if ((tid & 63) == 0) wsum[tid >> 6] = p;
    __syncthreads();
    if (tid == 0) c2out[0] = b2[0] + wsum[0] + wsum[1] + wsum[2] + wsum[3];
}

// ---------------- v[i][j] = sum_o up_w[i][o][j] * w2[o] ----------------
__global__ __launch_bounds__(64) void kv(const float* __restrict__ up_w, const float* __restrict__ w2,
                                         float* __restrict__ vmat) {
    int i = blockIdx.x, lane = threadIdx.x;
    float s0 = 0, s1 = 0, s2 = 0, s3 = 0, s4 = 0;
    for (int o = lane; o < TD; o += 64) {
        float w = w2[o];
        const float* p = up_w + (size_t)i * (TD * TU) + o * TU;
        s0 += p[0] * w; s1 += p[1] * w; s2 += p[2] * w; s3 += p[3] * w; s4 += p[4] * w;
    }
#pragma unroll
    for (int m = 1; m < 64; m <<= 1) {
        s0 += __shfl_xor(s0, m); s1 += __shfl_xor(s1, m); s2 += __shfl_xor(s2, m);
        s3 += __shfl_xor(s3, m); s4 += __shfl_xor(s4, m);
    }
    if (lane == 0) {
        float* d = vmat + i * TU;
        d[0] = s0; d[1] = s1; d[2] = s2; d[3] = s3; d[4] = s4;
    }
}

// ---------------- conv1d via fp16x3-split MFMA ----------------
// Block: 32 o x 256 t, 4 waves; wave = 32 o x 64 t = 2x4 C-tiles of 16x16.
// LDS ~50 KB -> 3 blocks/CU resident (occupancy was the round-4 bottleneck).
// K-loop over 32-channel chunks; 3 conv taps = B-row address offsets.
// fp32 emulated as Ah*Bh + Ah*Bl + Al*Bh (fp16 hi/lo split, err ~2^-22).
#define BSTR 72    // halves per B row: [h x32][l x32][pad x8]
#define ASTR 200   // halves per A row: 3 taps x ([h x32][l x32]) + pad 8
__global__ __launch_bounds__(256, 3) void kconvM(const float* __restrict__ enc, const float* __restrict__ cw,
                                                 const float* __restrict__ cb, const float* __restrict__ w1,
                                                 const float* __restrict__ vmat,
                                                 float* __restrict__ araw1, float* __restrict__ araw2) {
    __shared__ _Float16 sB[258 * BSTR];  // 37.1 KB  rows: s -> global t = t0-1+s
    __shared__ _Float16 sA[32 * ASTR];   // 12.8 KB  rows: o-local

    const int tid = threadIdx.x;
    const int t0 = blockIdx.x * 256;
    const int o0 = blockIdx.y * 32;
    const int b = blockIdx.z;
    const int wv = tid >> 6, lane = tid & 63;
    const int q = lane >> 4, l15 = lane & 15;

    float4t acc[2][4];
#pragma unroll
    for (int i = 0; i < 2; ++i)
#pragma unroll
        for (int j = 0; j < 4; ++j) acc[i][j] = (float4t){0.f, 0.f, 0.f, 0.f};

    for (int i0 = 0; i0 < TD; i0 += 32) {
        __syncthreads();
        // ---- stage B: enc window rows s=0..257 (t = t0-1+s), 32 channels, split h/l ----
        for (int u = tid; u < 258 * 16; u += 256) {
            int s = u >> 4, ii2 = (u & 15) << 1;
            int t = t0 - 1 + s;
            float x0 = 0.f, x1 = 0.f;
            if (t >= 0 && t < TT) {
                const float* p = &enc[((size_t)b * TT + t) * TD + i0 + ii2];
                x0 = p[0]; x1 = p[1];
            }
            _Float16 h0 = (_Float16)x0, h1 = (_Float16)x1;
            _Float16 l0 = (_Float16)(x0 - (float)h0), l1 = (_Float16)(x1 - (float)h1);
            half2t hh; hh[0] = h0; hh[1] = h1;
            half2t ll; ll[0] = l0; ll[1] = l1;
            *(half2t*)&sB[s * BSTR + ii2] = hh;
            *(half2t*)&sB[s * BSTR + 32 + ii2] = ll;
        }
        // ---- stage A: cw[o0..o0+32][i0..i0+32][k=0..2], split h/l ----
        for (int u = tid; u < 32 * 16; u += 256) {
            int o = u >> 4, ii2 = (u & 15) << 1;
            const float* p = &cw[((size_t)(o0 + o) * TD + i0 + ii2) * 3];
#pragma unroll
            for (int k = 0; k < 3; ++k) {
                float x0 = p[k], x1 = p[3 + k];
                _Float16 h0 = (_Float16)x0, h1 = (_Float16)x1;
                _Float16 l0 = (_Float16)(x0 - (float)h0), l1 = (_Float16)(x1 - (float)h1);
                half2t hh; hh[0] = h0; hh[1] = h1;
                half2t ll; ll[0] = l0; ll[1] = l1;
                *(half2t*)&sA[o * ASTR + k * 64 + ii2] = hh;
                *(half2t*)&sA[o * ASTR + k * 64 + 32 + ii2] = ll;
            }
        }
        __syncthreads();
        // ---- MFMA: 3 taps x 2 ot x 4 tt x 3 products ----
#pragma unroll
        for (int tap = 0; tap < 3; ++tap) {
            half8 Bh[4], Bl[4];
#pragma unroll
            for (int tt = 0; tt < 4; ++tt) {
                int s = wv * 64 + tt * 16 + l15 + tap;  // t_local + tap
                Bh[tt] = *(const half8*)&sB[s * BSTR + q * 8];
                Bl[tt] = *(const half8*)&sB[s * BSTR + 32 + q * 8];
            }
#pragma unroll
            for (int ot = 0; ot < 2; ++ot) {
                const int orow = ot * 16 + l15;
                half8 Ah = *(const half8*)&sA[orow * ASTR + tap * 64 + q * 8];
                half8 Al = *(const half8*)&sA[orow * ASTR + tap * 64 + 32 + q * 8];
#pragma unroll
                for (int tt = 0; tt < 4; ++tt) {
                    acc[ot][tt] = __builtin_amdgcn_mfma_f32_16x16x32_f16(Ah, Bh[tt], acc[ot][tt], 0, 0, 0);
                    acc[ot][tt] = __builtin_amdgcn_mfma_f32_16x16x32_f16(Ah, Bl[tt], acc[ot][tt], 0, 0, 0);
                    acc[ot][tt] = __builtin_amdgcn_mfma_f32_16x16x32_f16(Al, Bh[tt], acc[ot][tt], 0, 0, 0);
                }
            }
        }
    }

    // ---- epilogue: r=relu(conv+cb); 6 dots over this block's 32 o; reduce over quads; atomics ----
#pragma unroll
    for (int tt = 0; tt < 4; ++tt) {
        int t = t0 + wv * 64 + tt * 16 + l15;
        float s1 = 0.f, sa = 0.f, sb = 0.f, sc = 0.f, sd = 0.f, se = 0.f;
#pragma unroll
        for (int ot = 0; ot < 2; ++ot) {
#pragma unroll
            for (int r = 0; r < 4; ++r) {
                int o = o0 + ot * 16 + q * 4 + r;  // C row = quad*4 + reg
                float rv = fmaxf(acc[ot][tt][r] + cb[o], 0.f);
                s1 = fmaf(w1[o], rv, s1);
                const float* vp = &vmat[o * 5];
                sa = fmaf(vp[0], rv, sa); sb = fmaf(vp[1], rv, sb);
                sc = fmaf(vp[2], rv, sc); sd = fmaf(vp[3], rv, sd);
                se = fmaf(vp[4], rv, se);
            }
        }
        // reduce across the 4 quads (lane bits 4,5) — same t-column, different o-rows
        s1 += __shfl_xor(s1, 16); sa += __shfl_xor(sa, 16); sb += __shfl_xor(sb, 16);
        sc += __shfl_xor(sc, 16); sd += __shfl_xor(sd, 16); se += __shfl_xor(se, 16);
        s1 += __shfl_xor(s1, 32); sa += __shfl_xor(sa, 32); sb += __shfl_xor(sb, 32);
        sc += __shfl_xor(sc, 32); sd += __shfl_xor(sd, 32); se += __shfl_xor(se, 32);
        if (q == 0 && t < TT) {
            atomicAdd(&araw1[b * TT + t], s1);
            float* p2 = &araw2[(b * TT + t) * 5];
            atomicAdd(p2 + 0, sa); atomicAdd(p2 + 1, sb); atomicAdd(p2 + 2, sc);
            atomicAdd(p2 + 3, sd); atomicAdd(p2 + 4, se);
        }
    }
}

// ---------------- alphas_t (with tail), token_num2 ----------------
__global__ __launch_bounds__(256) void kalpha(const float* __restrict__ araw1, const float* __restrict__ araw2,
                                              const float* __restrict__ mask, const float* __restrict__ b1,
                                              const float* __restrict__ c2,
                                              float* __restrict__ alphas_t, float* __restrict__ tok2) {
    int b = blockIdx.y;
    int t = blockIdx.x * 256 + threadIdx.x;
    float sum5 = 0.f;
    if (t < TT) {
        float mk = mask[b * TT + t];
        float a1 = araw1[b * TT + t] + b1[0];
        float alpha = mk / (1.f + expf(-a1));
        float mprev = (t == 0) ? 1.f : mask[b * TT + t - 1];
        float tail = (mprev - mk) * 0.45f;
        alphas_t[b * TT1 + t] = alpha + tail;
        float cc = c2[0];
        float x0 = araw2[(b * TT + t) * 5 + 0] + cc;
        float x1 = araw2[(b * TT + t) * 5 + 1] + cc;
        float x2 = araw2[(b * TT + t) * 5 + 2] + cc;
        float x3 = araw2[(b * TT + t) * 5 + 3] + cc;
        float x4 = araw2[(b * TT + t) * 5 + 4] + cc;
        sum5 = mk / (1.f + expf(-x0)) + mk / (1.f + expf(-x1)) + mk / (1.f + expf(-x2))
             + mk / (1.f + expf(-x3)) + mk / (1.f + expf(-x4));
    } else if (t == TT) {
        alphas_t[b * TT1 + TT] = mask[b * TT + TT - 1] * 0.45f;
    }
#pragma unroll
    for (int m = 1; m < 64; m <<= 1) sum5 += __shfl_xor(sum5, m);
    if ((threadIdx.x & 63) == 0) atomicAdd(&tok2[b], sum5);
}

// ---------------- sequential CIF scan (faithful to reference fp32 op order) ----------------
__global__ __launch_bounds__(64) void kscan(const float* __restrict__ alphas_t,
                                            float* __restrict__ cif_peak, float* __restrict__ token_num,
                                            float* __restrict__ wA, float* __restrict__ wB,
                                            int* __restrict__ fire_time, int* __restrict__ n_fires) {
    int b = blockIdx.x, lane = threadIdx.x;
    float integ = 0.f, Ssum = 0.f;
    int F = 0;
    for (int c = 0; c < 16; ++c) {
        int t = c * 64 + lane;
        float av = (t < TT1) ? alphas_t[b * TT1 + t] : 0.f;
        float myPeak = 0.f, myWA = 0.f, myWB = 0.f;
        int myFire = 0, myF = 0;
        for (int j = 0; j < 64; ++j) {
            float a = __shfl(av, j);
            if (c * 64 + j < TT1) {
                float dist = 1.f - integ;
                integ += a;
                float peak = integ;
                bool fire = integ >= 1.f;
                float cur = fire ? dist : a;
                if (lane == j) {
                    myPeak = peak;
                    myWA = cur;
                    myWB = fire ? (a - cur) : 0.f;
                    myFire = fire ? 1 : 0;
                    myF = F;
                }
                if (fire) { integ -= 1.f; F++; }
                Ssum += a;
            }
        }
        if (t < TT1) {
            cif_peak[b * TT1 + t] = myPeak;
            wA[b * TT1 + t] = myWA;
            wB[b * TT1 + t] = myWB;
            if (myFire) fire_time[b * TT1 + myF] = t;
        }
    }
    if (lane == 0) {
        token_num[b] = floorf(Ssum);
        n_fires[b] = F;
    }
}

// ---------------- gather: acoustic[b,k,:] = segmented weighted sum of encoder rows ----------------
__global__ __launch_bounds__(128) void kgather(const float* __restrict__ enc,
                                               const float* __restrict__ wA, const float* __restrict__ wB,
                                               const int* __restrict__ fire_time, const int* __restrict__ n_fires,
                                               float* __restrict__ acoustic) {
    int k = blockIdx.x, b = blockIdx.y;
    int d4 = threadIdx.x;
    float ox = 0.f, oy = 0.f, oz = 0.f, ow = 0.f;
    int nf = n_fires[b];
    if (k < nf) {
        int end = fire_time[b * TT1 + k];
        int start = (k > 0) ? fire_time[b * TT1 + k - 1] : 0;
        for (int t = start; t <= end; ++t) {
            if (t >= TT) continue;
            float w = (k > 0 && t == start) ? wB[b * TT1 + t] : wA[b * TT1 + t];
            float4 h = ((const float4*)(enc + ((size_t)b * TT + t) * TD))[d4];
            ox += w * h.x; oy += w * h.y; oz += w * h.z; ow += w * h.w;
        }
    }
    float4 o4; o4.x = ox; o4.y = oy; o4.z = oz; o4.w = ow;
    ((float4*)(acoustic + ((size_t)b * TT1 + k) * TD))[d4] = o4;
}

extern "C" void kernel_launch(void* const* d_in, const int* in_sizes, int n_in,
                              void* d_out, int out_size, void* d_ws, size_t ws_size,
                              hipStream_t stream) {
    (void)in_sizes; (void)n_in; (void)out_size; (void)ws_size;
    const float* enc = (const float*)d_in[0];
    const float* mask = (const float*)d_in[1];
    const float* cw = (const float*)d_in[2];
    const float* cb = (const float*)d_in[3];
    const float* upw = (const float*)d_in[4];
    const float* upb = (const float*)d_in[5];
    const float* w1 = (const float*)d_in[6];
    const float* b1 = (const float*)d_in[7];
    const float* w2 = (const float*)d_in[8];
    const float* b2 = (const float*)d_in[9];

    float* out = (float*)d_out;
    float* acoustic = out + OFF_ACC;
    float* token_num = out + OFF_TOKN;
    float* alphas_t = out + OFF_ALPH;
    float* cif_peak = out + OFF_PEAK;
    float* tok2 = out + OFF_TOK2;

    float* ws = (float*)d_ws;
    float* araw1 = ws;                       // 32*1000
    float* araw2 = araw1 + TB * TT;          // 32*1000*5
    float* vmat = araw2 + TB * TT * TU;      // 512*5
    float* c2 = vmat + TD * TU;              // 1 (pad to 4)
    float* wA = c2 + 4;                      // 32*1001
    float* wB = wA + TB * TT1;               // 32*1001
    int* fire_time = (int*)(wB + TB * TT1);  // 32*1001
    int* n_fires = fire_time + TB * TT1;     // 32

    hipLaunchKernelGGL(kzero, dim3(256), dim3(256), 0, stream, araw1, araw2, tok2);
    hipLaunchKernelGGL(kc2, dim3(1), dim3(256), 0, stream, upb, w2, b2, c2);
    hipLaunchKernelGGL(kv, dim3(TD), dim3(64), 0, stream, upw, w2, vmat);
    hipLaunchKernelGGL(kconvM, dim3(4, 16, TB), dim3(256), 0, stream, enc, cw, cb, w1, vmat, araw1, araw2);
    hipLaunchKernelGGL(kalpha, dim3(4, TB), dim3(256), 0, stream, araw1, araw2, mask, b1, c2, alphas_t, tok2);
    hipLaunchKernelGGL(kscan, dim3(TB), dim3(64), 0, stream, alphas_t, cif_peak, token_num, wA, wB, fire_time, n_fires);
    hipLaunchKernelGGL(kgather, dim3(TT1, TB), dim3(128), 0, stream, enc, wA, wB, fire_time, n_fires, acoustic);
}

// Round 6
// 408.048 us; speedup vs baseline: 3.5222x; 1.7581x over previous
//
#include <hip/hip_runtime.h>
#include <math.h>

#define TB 32
#define TT 1000
#define TD 512
#define TU 5
#define TT1 1001

// d_out float offsets (return order: acoustic, token_num, alphas_t, cif_peak, token_num2)
#define OFF_ACC  0
#define OFF_TOKN 16400384
#define OFF_ALPH 16400416
#define OFF_PEAK 16432448
#define OFF_TOK2 16464480

typedef _Float16 half8 __attribute__((ext_vector_type(8)));
typedef _Float16 half2t __attribute__((ext_vector_type(2)));
typedef float float4t __attribute__((ext_vector_type(4)));

// global_load_lds: 16B per lane, LDS dest = wave-uniform base + lane*16 (m97 pattern)
typedef __attribute__((address_space(3))) uint32_t lds_u32_t;
typedef __attribute__((address_space(1))) const uint32_t g_u32_t;
#define GLOAD_LDS(gp, lp) __builtin_amdgcn_global_load_lds((g_u32_t*)(gp), (lds_u32_t*)(lp), 16, 0, 0)

#define BSTR 72    // halves per B row: [h x32][l x32][pad x8]
#define ASTR 200   // halves per A row: 3 taps x ([h x32][l x32]) + pad 8
#define EROWS 1032 // encs rows per (b,ic): 1 front pad + 1000 + 31 back pad

// ws float-index layout (small region, both paths)
#define WS_ARAW1 0
#define WS_ARAW2 32000
#define WS_VMAT  192000
#define WS_C2    194560
#define WS_WA    194564
#define WS_WB    226596
#define WS_FIRE  258628
#define WS_NF    290660
// big region (path A only), byte offsets
#define WS_ENCS_BYTES 1163264ull                      // float idx 290816
#define WS_CWS_BYTES  (WS_ENCS_BYTES + 76059648ull)   // encs = 32*16*1032*72*2 B
#define WS_NEED_BYTES (WS_CWS_BYTES + 3276800ull)     // cws  = 16*16*32*200*2 B

// ---------------- init: zero partial-dot accumulators + token_num2 ----------------
__global__ __launch_bounds__(256) void kzero(float* araw1, float* araw2, float* tok2) {
    int idx = blockIdx.x * 256 + threadIdx.x;
    int stride = gridDim.x * 256;
    for (int i = idx; i < TB * TT; i += stride) araw1[i] = 0.f;
    for (int i = idx; i < TB * TT * TU; i += stride) araw2[i] = 0.f;
    if (idx < TB) tok2[idx] = 0.f;
}

// ---------------- c2 = b2 + dot(up_b, w2) ----------------
__global__ __launch_bounds__(256) void kc2(const float* __restrict__ up_b, const float* __restrict__ w2,
                                           const float* __restrict__ b2, float* __restrict__ c2out) {
    int tid = threadIdx.x;
    float p = 0.f;
    for (int o = tid; o < TD; o += 256) p += up_b[o] * w2[o];
#pragma unroll
    for (int m = 1; m < 64; m <<= 1) p += __shfl_xor(p, m);
    __shared__ float wsum[4];
    if ((tid & 63) == 0) wsum[tid >> 6] = p;
    __syncthreads();
    if (tid == 0) c2out[0] = b2[0] + wsum[0] + wsum[1] + wsum[2] + wsum[3];
}

// ---------------- v[i][j] = sum_o up_w[i][o][j] * w2[o] ----------------
__global__ __launch_bounds__(64) void kv(const float* __restrict__ up_w, const float* __restrict__ w2,
                                         float* __restrict__ vmat) {
    int i = blockIdx.x, lane = threadIdx.x;
    float s0 = 0, s1 = 0, s2 = 0, s3 = 0, s4 = 0;
    for (int o = lane; o < TD; o += 64) {
        float w = w2[o];
        const float* p = up_w + (size_t)i * (TD * TU) + o * TU;
        s0 += p[0] * w; s1 += p[1] * w; s2 += p[2] * w; s3 += p[3] * w; s4 += p[4] * w;
    }
#pragma unroll
    for (int m = 1; m < 64; m <<= 1) {
        s0 += __shfl_xor(s0, m); s1 += __shfl_xor(s1, m); s2 += __shfl_xor(s2, m);
        s3 += __shfl_xor(s3, m); s4 += __shfl_xor(s4, m);
    }
    if (lane == 0) {
        float* d = vmat + i * TU;
        d[0] = s0; d[1] = s1; d[2] = s2; d[3] = s3; d[4] = s4;
    }
}

// ---------------- path A prep: split enc -> encs halves (h/l), BSTR layout ----------------
__global__ __launch_bounds__(256) void ksplitE(const float* __restrict__ enc, _Float16* __restrict__ encs) {
    int t = blockIdx.x, b = blockIdx.y, tid = threadIdx.x;
    int c = tid * 2;
    const float* p = &enc[((size_t)b * TT + t) * TD + c];
    float x0 = p[0], x1 = p[1];
    _Float16 h0 = (_Float16)x0, h1 = (_Float16)x1;
    _Float16 l0 = (_Float16)(x0 - (float)h0), l1 = (_Float16)(x1 - (float)h1);
    int ic = c >> 5, pos = c & 31;
    size_t base = ((size_t)(b * 16 + ic) * EROWS + 1 + t) * BSTR + pos;
    encs[base] = h0; encs[base + 1] = h1;
    encs[base + 32] = l0; encs[base + 33] = l1;
}

// zero encs pad rows (row 0 and rows 1001..1031 per bic) — re-poisoned each call
__global__ __launch_bounds__(256) void kpad(_Float16* __restrict__ encs) {
    uint32_t* p = (uint32_t*)encs;
    int idx = blockIdx.x * 256 + threadIdx.x;
    int stride = gridDim.x * 256;
    const int total = 512 * 32 * 36;  // bic x padrow x u32-per-row
    for (int u = idx; u < total; u += stride) {
        int bic = u / (32 * 36);
        int r = (u / 36) % 32;
        int w = u % 36;
        int row = (r == 0) ? 0 : 1000 + r;  // r=1..31 -> 1001..1031
        p[((size_t)bic * EROWS + row) * 36 + w] = 0u;
    }
}

// split cw -> cws tiles [oc][ic][o(32)][ASTR halves]
__global__ __launch_bounds__(64) void ksplitW(const float* __restrict__ cw, _Float16* __restrict__ cws) {
    int o = blockIdx.x, lane = threadIdx.x;
    for (int u = lane; u < 16 * 32 * 3; u += 64) {
        int tap = u % 3, pos = (u / 3) % 32, ic = u / 96;
        float x = cw[((size_t)o * TD + ic * 32 + pos) * 3 + tap];
        _Float16 h = (_Float16)x;
        _Float16 l = (_Float16)(x - (float)h);
        size_t base = (((size_t)(o >> 5) * 16 + ic) * 32 + (o & 31)) * ASTR + tap * 64;
        cws[base + pos] = h;
        cws[base + 32 + pos] = l;
    }
}

// ---------------- conv1d via fp16x3-split MFMA, DMA-staged (path A) ----------------
// Block: 32 o x 256 t, 4 waves. Staging via global_load_lds (no VALU, no ds_write).
__global__ __launch_bounds__(256, 3) void kconvMD(const _Float16* __restrict__ encs,
                                                  const _Float16* __restrict__ cws,
                                                  const float* __restrict__ cb, const float* __restrict__ w1,
                                                  const float* __restrict__ vmat,
                                                  float* __restrict__ araw1, float* __restrict__ araw2) {
    __shared__ _Float16 sB[258 * BSTR];  // 37.1 KB; LDS row s = data t = t0-1+s
    __shared__ _Float16 sA[32 * ASTR];   // 12.8 KB

    const int tid = threadIdx.x;
    const int t0 = blockIdx.x * 256;
    const int oc = blockIdx.y;
    const int b = blockIdx.z;
    const int o0 = oc * 32;
    const int wv = tid >> 6, lane = tid & 63;
    const int q = lane >> 4, l15 = lane & 15;

    float4t acc[2][4];
#pragma unroll
    for (int i = 0; i < 2; ++i)
#pragma unroll
        for (int j = 0; j < 4; ++j) acc[i][j] = (float4t){0.f, 0.f, 0.f, 0.f};

    for (int ic = 0; ic < 16; ++ic) {
        __syncthreads();
        // B tile: 258 rows x 144 B, contiguous in encs (front pad row makes t0-1 legal)
        const _Float16* gB = encs + ((size_t)(b * 16 + ic) * EROWS + t0) * BSTR;
        for (int c = tid; c < 2322; c += 256) GLOAD_LDS(gB + c * 8, &sB[c * 8]);
        // A tile: 32 rows x 400 B contiguous
        const _Float16* gA = cws + ((size_t)(oc * 16 + ic) * 32) * ASTR;
        for (int c = tid; c < 800; c += 256) GLOAD_LDS(gA + c * 8, &sA[c * 8]);
        __syncthreads();
        // ---- MFMA: 3 taps x 2 ot x 4 tt x 3 products (identical order to round 5) ----
#pragma unroll
        for (int tap = 0; tap < 3; ++tap) {
            half8 Bh[4], Bl[4];
#pragma unroll
            for (int tt = 0; tt < 4; ++tt) {
                int s = wv * 64 + tt * 16 + l15 + tap;
                Bh[tt] = *(const half8*)&sB[s * BSTR + q * 8];
                Bl[tt] = *(const half8*)&sB[s * BSTR + 32 + q * 8];
            }
#pragma unroll
            for (int ot = 0; ot < 2; ++ot) {
                const int orow = ot * 16 + l15;
                half8 Ah = *(const half8*)&sA[orow * ASTR + tap * 64 + q * 8];
                half8 Al = *(const half8*)&sA[orow * ASTR + tap * 64 + 32 + q * 8];
#pragma unroll
                for (int tt = 0; tt < 4; ++tt) {
                    acc[ot][tt] = __builtin_amdgcn_mfma_f32_16x16x32_f16(Ah, Bh[tt], acc[ot][tt], 0, 0, 0);
                    acc[ot][tt] = __builtin_amdgcn_mfma_f32_16x16x32_f16(Ah, Bl[tt], acc[ot][tt], 0, 0, 0);
                    acc[ot][tt] = __builtin_amdgcn_mfma_f32_16x16x32_f16(Al, Bh[tt], acc[ot][tt], 0, 0, 0);
                }
            }
        }
    }

    // ---- epilogue: r=relu(conv+cb); 6 dots; quad reduce; atomics ----
#pragma unroll
    for (int tt = 0; tt < 4; ++tt) {
        int t = t0 + wv * 64 + tt * 16 + l15;
        float s1 = 0.f, sa = 0.f, sb = 0.f, sc = 0.f, sd = 0.f, se = 0.f;
#pragma unroll
        for (int ot = 0; ot < 2; ++ot) {
#pragma unroll
            for (int r = 0; r < 4; ++r) {
                int o = o0 + ot * 16 + q * 4 + r;
                float rv = fmaxf(acc[ot][tt][r] + cb[o], 0.f);
                s1 = fmaf(w1[o], rv, s1);
                const float* vp = &vmat[o * 5];
                sa = fmaf(vp[0], rv, sa); sb = fmaf(vp[1], rv, sb);
                sc = fmaf(vp[2], rv, sc); sd = fmaf(vp[3], rv, sd);
                se = fmaf(vp[4], rv, se);
            }
        }
        s1 += __shfl_xor(s1, 16); sa += __shfl_xor(sa, 16); sb += __shfl_xor(sb, 16);
        sc += __shfl_xor(sc, 16); sd += __shfl_xor(sd, 16); se += __shfl_xor(se, 16);
        s1 += __shfl_xor(s1, 32); sa += __shfl_xor(sa, 32); sb += __shfl_xor(sb, 32);
        sc += __shfl_xor(sc, 32); sd += __shfl_xor(sd, 32); se += __shfl_xor(se, 32);
        if (q == 0 && t < TT) {
            atomicAdd(&araw1[b * TT + t], s1);
            float* p2 = &araw2[(b * TT + t) * 5];
            atomicAdd(p2 + 0, sa); atomicAdd(p2 + 1, sb); atomicAdd(p2 + 2, sc);
            atomicAdd(p2 + 3, sd); atomicAdd(p2 + 4, se);
        }
    }
}

// ---------------- conv1d fallback (round-5 kernel, path B) ----------------
__global__ __launch_bounds__(256, 3) void kconvM(const float* __restrict__ enc, const float* __restrict__ cw,
                                                 const float* __restrict__ cb, const float* __restrict__ w1,
                                                 const float* __restrict__ vmat,
                                                 float* __restrict__ araw1, float* __restrict__ araw2) {
    __shared__ _Float16 sB[258 * BSTR];
    __shared__ _Float16 sA[32 * ASTR];

    const int tid = threadIdx.x;
    const int t0 = blockIdx.x * 256;
    const int o0 = blockIdx.y * 32;
    const int b = blockIdx.z;
    const int wv = tid >> 6, lane = tid & 63;
    const int q = lane >> 4, l15 = lane & 15;

    float4t acc[2][4];
#pragma unroll
    for (int i = 0; i < 2; ++i)
#pragma unroll
        for (int j = 0; j < 4; ++j) acc[i][j] = (float4t){0.f, 0.f, 0.f, 0.f};

    for (int i0 = 0; i0 < TD; i0 += 32) {
        __syncthreads();
        for (int u = tid; u < 258 * 16; u += 256) {
            int s = u >> 4, ii2 = (u & 15) << 1;
            int t = t0 - 1 + s;
            float x0 = 0.f, x1 = 0.f;
            if (t >= 0 && t < TT) {
                const float* p = &enc[((size_t)b * TT + t) * TD + i0 + ii2];
                x0 = p[0]; x1 = p[1];
            }
            _Float16 h0 = (_Float16)x0, h1 = (_Float16)x1;
            _Float16 l0 = (_Float16)(x0 - (float)h0), l1 = (_Float16)(x1 - (float)h1);
            half2t hh; hh[0] = h0; hh[1] = h1;
            half2t ll; ll[0] = l0; ll[1] = l1;
            *(half2t*)&sB[s * BSTR + ii2] = hh;
            *(half2t*)&sB[s * BSTR + 32 + ii2] = ll;
        }
        for (int u = tid; u < 32 * 16; u += 256) {
            int o = u >> 4, ii2 = (u & 15) << 1;
            const float* p = &cw[((size_t)(o0 + o) * TD + i0 + ii2) * 3];
#pragma unroll
            for (int k = 0; k < 3; ++k) {
                float x0 = p[k], x1 = p[3 + k];
                _Float16 h0 = (_Float16)x0, h1 = (_Float16)x1;
                _Float16 l0 = (_Float16)(x0 - (float)h0), l1 = (_Float16)(x1 - (float)h1);
                half2t hh; hh[0] = h0; hh[1] = h1;
                half2t ll; ll[0] = l0; ll[1] = l1;
                *(half2t*)&sA[o * ASTR + k * 64 + ii2] = hh;
                *(half2t*)&sA[o * ASTR + k * 64 + 32 + ii2] = ll;
            }
        }
        __syncthreads();
#pragma unroll
        for (int tap = 0; tap < 3; ++tap) {
            half8 Bh[4], Bl[4];
#pragma unroll
            for (int tt = 0; tt < 4; ++tt) {
                int s = wv * 64 + tt * 16 + l15 + tap;
                Bh[tt] = *(const half8*)&sB[s * BSTR + q * 8];
                Bl[tt] = *(const half8*)&sB[s * BSTR + 32 + q * 8];
            }
#pragma unroll
            for (int ot = 0; ot < 2; ++ot) {
                const int orow = ot * 16 + l15;
                half8 Ah = *(const half8*)&sA[orow * ASTR + tap * 64 + q * 8];
                half8 Al = *(const half8*)&sA[orow * ASTR + tap * 64 + 32 + q * 8];
#pragma unroll
                for (int tt = 0; tt < 4; ++tt) {
                    acc[ot][tt] = __builtin_amdgcn_mfma_f32_16x16x32_f16(Ah, Bh[tt], acc[ot][tt], 0, 0, 0);
                    acc[ot][tt] = __builtin_amdgcn_mfma_f32_16x16x32_f16(Ah, Bl[tt], acc[ot][tt], 0, 0, 0);
                    acc[ot][tt] = __builtin_amdgcn_mfma_f32_16x16x32_f16(Al, Bh[tt], acc[ot][tt], 0, 0, 0);
                }
            }
        }
    }

#pragma unroll
    for (int tt = 0; tt < 4; ++tt) {
        int t = t0 + wv * 64 + tt * 16 + l15;
        float s1 = 0.f, sa = 0.f, sb = 0.f, sc = 0.f, sd = 0.f, se = 0.f;
#pragma unroll
        for (int ot = 0; ot < 2; ++ot) {
#pragma unroll
            for (int r = 0; r < 4; ++r) {
                int o = o0 + ot * 16 + q * 4 + r;
                float rv = fmaxf(acc[ot][tt][r] + cb[o], 0.f);
                s1 = fmaf(w1[o], rv, s1);
                const float* vp = &vmat[o * 5];
                sa = fmaf(vp[0], rv, sa); sb = fmaf(vp[1], rv, sb);
                sc = fmaf(vp[2], rv, sc); sd = fmaf(vp[3], rv, sd);
                se = fmaf(vp[4], rv, se);
            }
        }
        s1 += __shfl_xor(s1, 16); sa += __shfl_xor(sa, 16); sb += __shfl_xor(sb, 16);
        sc += __shfl_xor(sc, 16); sd += __shfl_xor(sd, 16); se += __shfl_xor(se, 16);
        s1 += __shfl_xor(s1, 32); sa += __shfl_xor(sa, 32); sb += __shfl_xor(sb, 32);
        sc += __shfl_xor(sc, 32); sd += __shfl_xor(sd, 32); se += __shfl_xor(se, 32);
        if (q == 0 && t < TT) {
            atomicAdd(&araw1[b * TT + t], s1);
            float* p2 = &araw2[(b * TT + t) * 5];
            atomicAdd(p2 + 0, sa); atomicAdd(p2 + 1, sb); atomicAdd(p2 + 2, sc);
            atomicAdd(p2 + 3, sd); atomicAdd(p2 + 4, se);
        }
    }
}

// ---------------- alphas_t (with tail), token_num2 ----------------
__global__ __launch_bounds__(256) void kalpha(const float* __restrict__ araw1, const float* __restrict__ araw2,
                                              const float* __restrict__ mask, const float* __restrict__ b1,
                                              const float* __restrict__ c2,
                                              float* __restrict__ alphas_t, float* __restrict__ tok2) {
    int b = blockIdx.y;
    int t = blockIdx.x * 256 + threadIdx.x;
    float sum5 = 0.f;
    if (t < TT) {
        float mk = mask[b * TT + t];
        float a1 = araw1[b * TT + t] + b1[0];
        float alpha = mk / (1.f + expf(-a1));
        float mprev = (t == 0) ? 1.f : mask[b * TT + t - 1];
        float tail = (mprev - mk) * 0.45f;
        alphas_t[b * TT1 + t] = alpha + tail;
        float cc = c2[0];
        float x0 = araw2[(b * TT + t) * 5 + 0] + cc;
        float x1 = araw2[(b * TT + t) * 5 + 1] + cc;
        float x2 = araw2[(b * TT + t) * 5 + 2] + cc;
        float x3 = araw2[(b * TT + t) * 5 + 3] + cc;
        float x4 = araw2[(b * TT + t) * 5 + 4] + cc;
        sum5 = mk / (1.f + expf(-x0)) + mk / (1.f + expf(-x1)) + mk / (1.f + expf(-x2))
             + mk / (1.f + expf(-x3)) + mk / (1.f + expf(-x4));
    } else if (t == TT) {
        alphas_t[b * TT1 + TT] = mask[b * TT + TT - 1] * 0.45f;
    }
#pragma unroll
    for (int m = 1; m < 64; m <<= 1) sum5 += __shfl_xor(sum5, m);
    if ((threadIdx.x & 63) == 0) atomicAdd(&tok2[b], sum5);
}

// ---------------- sequential CIF scan: single-lane serial (same fp op order) ----------------
#define STEP(j, aj) { \
    float dist = 1.f - integ; \
    integ += (aj); \
    sp[tq + (j)] = integ; \
    bool fire = integ >= 1.f; \
    float cur = fire ? dist : (aj); \
    swa[tq + (j)] = cur; \
    swb[tq + (j)] = fire ? ((aj) - cur) : 0.f; \
    if (fire) { sf[F++] = tq + (j); integ -= 1.f; } \
    Ssum += (aj); }

__global__ __launch_bounds__(64) void kscan(const float* __restrict__ alphas_t,
                                            float* __restrict__ cif_peak, float* __restrict__ token_num,
                                            float* __restrict__ wA, float* __restrict__ wB,
                                            int* __restrict__ fire_time, int* __restrict__ n_fires) {
    __shared__ float sa[TT1 + 7], sp[TT1], swa[TT1], swb[TT1];
    __shared__ int sf[TT1];
    __shared__ int sFs;
    int b = blockIdx.x, lane = threadIdx.x;
    for (int t = lane; t < TT1 + 7; t += 64) sa[t] = (t < TT1) ? alphas_t[b * TT1 + t] : 0.f;
    __syncthreads();
    if (lane == 0) {
        float integ = 0.f, Ssum = 0.f;
        int F = 0;
        for (int tq = 0; tq < TT1 - 1; tq += 8) {  // 125 full chunks of 8 -> t=0..999
            float a0 = sa[tq], a1 = sa[tq + 1], a2 = sa[tq + 2], a3 = sa[tq + 3];
            float a4 = sa[tq + 4], a5 = sa[tq + 5], a6 = sa[tq + 6], a7 = sa[tq + 7];
            STEP(0, a0) STEP(1, a1) STEP(2, a2) STEP(3, a3)
            STEP(4, a4) STEP(5, a5) STEP(6, a6) STEP(7, a7)
        }
        { int tq = TT1 - 1; float a0 = sa[tq]; STEP(0, a0) }  // t = 1000
        token_num[b] = floorf(Ssum);
        n_fires[b] = F;
        sFs = F;
    }
    __syncthreads();
    int F = sFs;
    for (int t = lane; t < TT1; t += 64) {
        cif_peak[b * TT1 + t] = sp[t];
        wA[b * TT1 + t] = swa[t];
        wB[b * TT1 + t] = swb[t];
        if (t < F) fire_time[b * TT1 + t] = sf[t];
    }
}

// ---------------- gather: acoustic[b,k,:] = segmented weighted sum of encoder rows ----------------
__global__ __launch_bounds__(128) void kgather(const float* __restrict__ enc,
                                               const float* __restrict__ wA, const float* __restrict__ wB,
                                               const int* __restrict__ fire_time, const int* __restrict__ n_fires,
                                               float* __restrict__ acoustic) {
    int k = blockIdx.x, b = blockIdx.y;
    int d4 = threadIdx.x;
    float ox = 0.f, oy = 0.f, oz = 0.f, ow = 0.f;
    int nf = n_fires[b];
    if (k < nf) {
        int end = fire_time[b * TT1 + k];
        int start = (k > 0) ? fire_time[b * TT1 + k - 1] : 0;
        for (int t = start; t <= end; ++t) {
            if (t >= TT) continue;
            float w = (k > 0 && t == start) ? wB[b * TT1 + t] : wA[b * TT1 + t];
            float4 h = ((const float4*)(enc + ((size_t)b * TT + t) * TD))[d4];
            ox += w * h.x; oy += w * h.y; oz += w * h.z; ow += w * h.w;
        }
    }
    float4 o4; o4.x = ox; o4.y = oy; o4.z = oz; o4.w = ow;
    ((float4*)(acoustic + ((size_t)b * TT1 + k) * TD))[d4] = o4;
}

extern "C" void kernel_launch(void* const* d_in, const int* in_sizes, int n_in,
                              void* d_out, int out_size, void* d_ws, size_t ws_size,
                              hipStream_t stream) {
    (void)in_sizes; (void)n_in; (void)out_size;
    const float* enc = (const float*)d_in[0];
    const float* mask = (const float*)d_in[1];
    const float* cw = (const float*)d_in[2];
    const float* cb = (const float*)d_in[3];
    const float* upw = (const float*)d_in[4];
    const float* upb = (const float*)d_in[5];
    const float* w1 = (const float*)d_in[6];
    const float* b1 = (const float*)d_in[7];
    const float* w2 = (const float*)d_in[8];
    const float* b2 = (const float*)d_in[9];

    float* out = (float*)d_out;
    float* acoustic = out + OFF_ACC;
    float* token_num = out + OFF_TOKN;
    float* alphas_t = out + OFF_ALPH;
    float* cif_peak = out + OFF_PEAK;
    float* tok2 = out + OFF_TOK2;

    float* ws = (float*)d_ws;
    float* araw1 = ws + WS_ARAW1;
    float* araw2 = ws + WS_ARAW2;
    float* vmat = ws + WS_VMAT;
    float* c2 = ws + WS_C2;
    float* wA = ws + WS_WA;
    float* wB = ws + WS_WB;
    int* fire_time = (int*)(ws + WS_FIRE);
    int* n_fires = (int*)(ws + WS_NF);
    _Float16* encs = (_Float16*)((char*)d_ws + WS_ENCS_BYTES);
    _Float16* cws = (_Float16*)((char*)d_ws + WS_CWS_BYTES);

    const bool bigws = (ws_size >= WS_NEED_BYTES);  // constant across calls -> graph-safe

    hipLaunchKernelGGL(kzero, dim3(256), dim3(256), 0, stream, araw1, araw2, tok2);
    hipLaunchKernelGGL(kc2, dim3(1), dim3(256), 0, stream, upb, w2, b2, c2);
    hipLaunchKernelGGL(kv, dim3(TD), dim3(64), 0, stream, upw, w2, vmat);
    if (bigws) {
        hipLaunchKernelGGL(kpad, dim3(1024), dim3(256), 0, stream, encs);
        hipLaunchKernelGGL(ksplitE, dim3(TT, TB), dim3(256), 0, stream, enc, encs);
        hipLaunchKernelGGL(ksplitW, dim3(TD), dim3(64), 0, stream, cw, cws);
        hipLaunchKernelGGL(kconvMD, dim3(4, 16, TB), dim3(256), 0, stream, encs, cws, cb, w1, vmat, araw1, araw2);
    } else {
        hipLaunchKernelGGL(kconvM, dim3(4, 16, TB), dim3(256), 0, stream, enc, cw, cb, w1, vmat, araw1, araw2);
    }
    hipLaunchKernelGGL(kalpha, dim3(4, TB), dim3(256), 0, stream, araw1, araw2, mask, b1, c2, alphas_t, tok2);
    hipLaunchKernelGGL(kscan, dim3(TB), dim3(64), 0, stream, alphas_t, cif_peak, token_num, wA, wB, fire_time, n_fires);
    hipLaunchKernelGGL(kgather, dim3(TT1, TB), dim3(128), 0, stream, enc, wA, wB, fire_time, n_fires, acoustic);
}